// Round 5
// baseline (1408.483 us; speedup 1.0000x reference)
//
#include <hip/hip_runtime.h>

#define B_SZ 4
#define T_SZ 2048
#define C_SZ 2048
#define H_SZ 16
#define D_SZ 128

typedef __attribute__((ext_vector_type(8))) __bf16 bf16x8;
typedef __attribute__((ext_vector_type(4))) float f32x4;
typedef __attribute__((ext_vector_type(4))) unsigned short us4;

// RNE f32->bf16 bit-trick. VERIFIED: this is the only correct RNE path on this
// toolchain — both (__bf16) casts and v_cvt_pk_bf16_f32 TRUNCATE (R3/R4 fails:
// coherent 0.5-ulp bias over K=2048 dot products -> absmax 0.11-0.34).
static __device__ __forceinline__ unsigned short f2bf(float f) {
  unsigned u = __builtin_bit_cast(unsigned, f);
  u += 0x7fffu + ((u >> 16) & 1u);
  return (unsigned short)(u >> 16);
}

static __device__ __forceinline__ void gload16(const void* g, void* l) {
  __builtin_amdgcn_global_load_lds((__attribute__((address_space(1))) void*)(g),
                                   (__attribute__((address_space(3))) void*)(l), 16, 0, 0);
}

__global__ __launch_bounds__(256) void cast_f32_bf16(const float* __restrict__ src,
                                                     unsigned short* __restrict__ dst, int n4) {
  int i = blockIdx.x * 256 + threadIdx.x;
  if (i >= n4) return;
  float4 v = ((const float4*)src)[i];
  us4 o;
  o[0] = f2bf(v.x); o[1] = f2bf(v.y); o[2] = f2bf(v.z); o[3] = f2bf(v.w);
  ((us4*)dst)[i] = o;
}

// C[m,n] = sum_k A[m,k]*W[n,k].  A: MxK bf16 row-major, W: NxK bf16 row-major.
// m201-style phase template: BM=BN=256, BK=64, 512 thr = 8 waves (4M x 2N),
// per-wave 64x128 output (acc[4][8]).  Double-buffered LDS tiles (128 KB).
// Per K-tile: 4 phases, each {ds_read quadrant frags; barrier; setprio(1);
// 16 MFMA; setprio(0); barrier}.  All 8 global_load_lds for tile t+1 issue at
// the top of iter t (slot is dead since end of iter t-1); one counted
// s_waitcnt vmcnt(8) per K-tile keeps them in flight across barriers (T4).
// LDS XOR-swizzle (T2): 16B col-chunk ^= (row&7), applied by pre-permuting the
// per-lane GLOBAL source (linear gload_lds dest) and on the ds_read address.
// EPI 1: RoPE epilogue -> bf16; EPI 2: transposed store -> Vt; EPI 3: fp32 store
template <int EPI>
__global__ __launch_bounds__(512, 2) void gemm_bt(const unsigned short* __restrict__ A,
                                                  const unsigned short* __restrict__ W,
                                                  void* __restrict__ out,
                                                  const float* __restrict__ cosp,
                                                  const float* __restrict__ sinp,
                                                  float outScale, int M, int N, int K) {
  __shared__ unsigned short As[2][256 * 64];  // 2 x 32 KB
  __shared__ unsigned short Bs[2][256 * 64];  // 2 x 32 KB
  const int tid = threadIdx.x;
  const int wave = tid >> 6, lane = tid & 63, quad = lane >> 4, l15 = lane & 15;
  const int wm = wave >> 1, wn = wave & 1;
  const int m0 = blockIdx.y * 256, n0 = blockIdx.x * 256;
  const int NT = K >> 6;

  // staging: per operand slot = 2048 chunks of 16B; chunk i: row=i>>3, c8=i&7,
  // swizzled k-chunk = c8 ^ (row&7).  thread covers chunks j*512+tid, j=0..3.
  const int srow = tid >> 3;
  const int kcol = ((tid & 7) ^ (srow & 7)) * 8;
  const unsigned short* aptr = A + (size_t)(m0 + srow) * K + kcol;
  const unsigned short* bptr = W + (size_t)(n0 + srow) * K + kcol;
  const int ldst = tid * 16;  // byte offset of chunk j=0 in a slot

#define STAGE(t)                                                                   \
  do {                                                                             \
    const int sl_ = (t) & 1;                                                       \
    const size_t kk_ = (size_t)(t) * 64;                                           \
    _Pragma("unroll") for (int j = 0; j < 4; ++j) {                                \
      gload16(aptr + (size_t)j * 64 * K + kk_, (char*)As[sl_] + j * 8192 + ldst);  \
      gload16(bptr + (size_t)j * 64 * K + kk_, (char*)Bs[sl_] + j * 8192 + ldst);  \
    }                                                                              \
  } while (0)

  f32x4 acc[4][8] = {};
  const int swz = l15 & 7;

  STAGE(0);  // 8 loads in flight
  for (int t = 0; t < NT; ++t) {
    if (t + 1 < NT) {
      STAGE(t + 1);  // now up to 16 in flight
      asm volatile("s_waitcnt vmcnt(8)" ::: "memory");  // tile t landed; t+1 stays in flight
    } else {
      asm volatile("s_waitcnt vmcnt(0)" ::: "memory");  // tail drain (once)
    }
    __builtin_amdgcn_s_barrier();
    asm volatile("" ::: "memory");
    const unsigned short* Asl = As[t & 1];
    const unsigned short* Bsl = Bs[t & 1];
    bf16x8 af[4];
#pragma unroll
    for (int p = 0; p < 4; ++p) {
      const int ks = p >> 1, nh = p & 1;  // quadrant = (kstep, n-half)
      if (nh == 0) {
#pragma unroll
        for (int mf = 0; mf < 4; ++mf)
          af[mf] = *(const bf16x8*)&Asl[(wm * 64 + mf * 16 + l15) * 64 +
                                        (((ks * 4 + quad) ^ swz) * 8)];
      }
      bf16x8 bfr[4];
#pragma unroll
      for (int i = 0; i < 4; ++i)
        bfr[i] = *(const bf16x8*)&Bsl[(wn * 128 + (nh * 4 + i) * 16 + l15) * 64 +
                                      (((ks * 4 + quad) ^ swz) * 8)];
      __builtin_amdgcn_s_barrier();  // align waves at MFMA entry
      asm volatile("" ::: "memory");
      __builtin_amdgcn_s_setprio(1);
#pragma unroll
      for (int i = 0; i < 4; ++i)
#pragma unroll
        for (int mf = 0; mf < 4; ++mf)
          acc[mf][nh * 4 + i] =
              __builtin_amdgcn_mfma_f32_16x16x32_bf16(af[mf], bfr[i], acc[mf][nh * 4 + i], 0, 0, 0);
      __builtin_amdgcn_s_setprio(0);
      __builtin_amdgcn_s_barrier();
      asm volatile("" ::: "memory");
    }
  }
#undef STAGE

  const int mb = m0 + wm * 64, nb = n0 + wn * 128;
  if (EPI == 1) {
    unsigned short* O = (unsigned short*)out;
#pragma unroll
    for (int mf = 0; mf < 4; ++mf)
#pragma unroll
      for (int r = 0; r < 4; ++r) {
        int m = mb + mf * 16 + quad * 4 + r;
        int tt = m & (T_SZ - 1);
#pragma unroll
        for (int nf = 0; nf < 4; ++nf) {
          int dd = nf * 16 + l15;
          float c = cosp[tt * 64 + dd];
          float s = sinp[tt * 64 + dd];
          float x1 = acc[mf][nf][r], x2 = acc[mf][nf + 4][r];
          O[(size_t)m * N + nb + dd]      = f2bf((x1 * c + x2 * s) * outScale);
          O[(size_t)m * N + nb + dd + 64] = f2bf((x1 * c - x2 * s) * outScale);
        }
      }
  } else if (EPI == 2) {
    unsigned short* O = (unsigned short*)out;
#pragma unroll
    for (int mf = 0; mf < 4; ++mf) {
      int m4 = mb + mf * 16 + quad * 4;  // 4 consecutive rows (same b)
      int bb = m4 >> 11;
      int tt = m4 & (T_SZ - 1);
#pragma unroll
      for (int nf = 0; nf < 8; ++nf) {
        int n = nb + nf * 16 + l15;
        int h = n >> 7, d = n & (D_SZ - 1);
        us4 pk;
        pk[0] = f2bf(acc[mf][nf][0]);
        pk[1] = f2bf(acc[mf][nf][1]);
        pk[2] = f2bf(acc[mf][nf][2]);
        pk[3] = f2bf(acc[mf][nf][3]);
        *(us4*)&O[((size_t)((bb * H_SZ + h) * D_SZ + d)) * T_SZ + tt] = pk;
      }
    }
  } else {
    float* O = (float*)out;
#pragma unroll
    for (int mf = 0; mf < 4; ++mf)
#pragma unroll
      for (int nf = 0; nf < 8; ++nf)
#pragma unroll
        for (int r = 0; r < 4; ++r) {
          int m = mb + mf * 16 + quad * 4 + r;
          O[(size_t)m * N + nb + nf * 16 + l15] = acc[mf][nf][r];
        }
  }
}

static __device__ __forceinline__ void stage_k(const unsigned short* __restrict__ Kg,
                                               unsigned short* Kbuf,
                                               size_t kbase0, int kt, int tid) {
  size_t kb = kbase0 + (size_t)kt * 64 * C_SZ;
#pragma unroll
  for (int s = 0; s < 4; ++s) {
    int ii = s * 256 + tid;
    int krow = ii >> 4, kpos = ii & 15, kc = kpos ^ (krow & 15);
    gload16(Kg + kb + (size_t)krow * C_SZ + kc * 8, (char*)Kbuf + ii * 16);
  }
}

// Flash attention v8 = R2's v6 with V read DIRECTLY from global (Vt is
// L2-resident: 1 MB KV per head shared by 32 qt-blocks; bv fragments are
// loaded a full softmax-phase before PV use).  Drops Vs (32 KB LDS) ->
// 42 KB total -> 3 blocks/CU (was 2).  Numerics bit-identical to R2:
// manual-RNE f2bf everywhere, same MFMA order, same sync structure.
__global__ __launch_bounds__(256, 3) void attn_fused(const unsigned short* __restrict__ Q,
                                                     const unsigned short* __restrict__ Kg,
                                                     const unsigned short* __restrict__ Vt,
                                                     unsigned short* __restrict__ Y) {
  __shared__ unsigned short Ks[2][64 * 128];   // 32 KB (dbuf)
  __shared__ unsigned short Ps[4][32 * 40];    // 10 KB, per-wave P[q32][kv32]
  const int tid = threadIdx.x;
  const int wave = tid >> 6, lane = tid & 63, quad = lane >> 4, l15 = lane & 15;
  const int kh = wave & 1, qh = wave >> 1;
  const int qt = blockIdx.x, bh = blockIdx.y;
  const int b = bh >> 4, h = bh & 15;
  const float LOG2E = 1.44269504088896f;

  // Q fragments direct to registers (B-operand: n=q in l15, k contiguous)
  bf16x8 aq[2][4];
  {
    size_t qrow0 = (size_t)(b * T_SZ + qt * 64 + qh * 32);
#pragma unroll
    for (int nt = 0; nt < 2; ++nt)
#pragma unroll
      for (int ks = 0; ks < 4; ++ks)
        aq[nt][ks] = *(const bf16x8*)(Q + (qrow0 + nt * 16 + l15) * C_SZ + h * D_SZ + ks * 32 + quad * 8);
  }

  const size_t kbase0 = ((size_t)(b * T_SZ)) * C_SZ + h * D_SZ;
  const size_t vbase0 = ((size_t)(bh * D_SZ)) * T_SZ;
  // per-lane V row pointer: row d = dt*16 + l15, kv col = (kh*4+quad)*8 within
  // the 64-kv tile (wave kh's 32-kv window = cols kh*32 + quad*8 .. +8)
  const unsigned short* Vrow = Vt + vbase0 + (size_t)l15 * T_SZ + (kh * 4 + quad) * 8;
  stage_k(Kg, Ks[0], kbase0, 0, tid);
  stage_k(Kg, Ks[1], kbase0, 1, tid);

  float mstate[2] = {-1e30f, -1e30f}, lstate[2] = {0.f, 0.f};
  f32x4 o[8][2] = {};
  unsigned short* PsW = Ps[wave];
  __syncthreads();   // tiles 0,1 staged (vmcnt drained); aq ready

  for (int jt = 0; jt < T_SZ / 128; ++jt) {
    // ---- tile A (buf0): K frags -> regs, V frags <- global (L2), S_A
    bf16x8 bkA[2][4], bvA[8];
#pragma unroll
    for (int mt = 0; mt < 2; ++mt)
#pragma unroll
      for (int ks = 0; ks < 4; ++ks)
        bkA[mt][ks] = *(const bf16x8*)&Ks[0][(kh * 32 + mt * 16 + l15) * 128 + (((ks * 4 + quad) ^ l15) * 8)];
#pragma unroll
    for (int dt = 0; dt < 8; ++dt)
      bvA[dt] = *(const bf16x8*)(Vrow + (size_t)dt * 16 * T_SZ + jt * 128);
    f32x4 sfA[2][2] = {};
#pragma unroll
    for (int mt = 0; mt < 2; ++mt)
#pragma unroll
      for (int ks = 0; ks < 4; ++ks)
#pragma unroll
        for (int nt = 0; nt < 2; ++nt)
          sfA[mt][nt] = __builtin_amdgcn_mfma_f32_16x16x32_bf16(bkA[mt][ks], aq[nt][ks], sfA[mt][nt], 0, 0, 0);
    __syncthreads();                       // buf0 consumed by all waves
    if (jt + 1 < T_SZ / 128) stage_k(Kg, Ks[0], kbase0, 2 * jt + 2, tid);
    // ---- tile B (buf1): K frags -> regs, V frags <- global, S_B
    bf16x8 bkB[2][4], bvB[8];
#pragma unroll
    for (int mt = 0; mt < 2; ++mt)
#pragma unroll
      for (int ks = 0; ks < 4; ++ks)
        bkB[mt][ks] = *(const bf16x8*)&Ks[1][(kh * 32 + mt * 16 + l15) * 128 + (((ks * 4 + quad) ^ l15) * 8)];
#pragma unroll
    for (int dt = 0; dt < 8; ++dt)
      bvB[dt] = *(const bf16x8*)(Vrow + (size_t)dt * 16 * T_SZ + jt * 128 + 64);
    f32x4 sfB[2][2] = {};
#pragma unroll
    for (int mt = 0; mt < 2; ++mt)
#pragma unroll
      for (int ks = 0; ks < 4; ++ks)
#pragma unroll
        for (int nt = 0; nt < 2; ++nt)
          sfB[mt][nt] = __builtin_amdgcn_mfma_f32_16x16x32_bf16(bkB[mt][ks], aq[nt][ks], sfB[mt][nt], 0, 0, 0);
    // ---- paired online softmax (e-base, fp32 LOG2E; q = nt*16+l15 per-lane scalar)
    float alpha[2], rsum[2];
#pragma unroll
    for (int nt = 0; nt < 2; ++nt) {
      float rmax = sfA[0][nt][0];
#pragma unroll
      for (int mt = 0; mt < 2; ++mt)
#pragma unroll
        for (int r = 0; r < 4; ++r) {
          rmax = fmaxf(rmax, sfA[mt][nt][r]);
          rmax = fmaxf(rmax, sfB[mt][nt][r]);
        }
      rmax = fmaxf(rmax, __shfl_xor(rmax, 16));
      rmax = fmaxf(rmax, __shfl_xor(rmax, 32));
      float mnew = fmaxf(mstate[nt], rmax);
      alpha[nt] = exp2f((mstate[nt] - mnew) * LOG2E);
      mstate[nt] = mnew;
      rsum[nt] = 0.f;
    }
    // one O-rescale per 128 kv
#pragma unroll
    for (int dt = 0; dt < 8; ++dt)
#pragma unroll
      for (int nt = 0; nt < 2; ++nt)
        o[dt][nt] *= alpha[nt];
    // P_A -> Ps (RNE), PV_A
#pragma unroll
    for (int nt = 0; nt < 2; ++nt)
#pragma unroll
      for (int mt = 0; mt < 2; ++mt) {
        us4 pk;
        float p0 = exp2f((sfA[mt][nt][0] - mstate[nt]) * LOG2E);
        float p1 = exp2f((sfA[mt][nt][1] - mstate[nt]) * LOG2E);
        float p2 = exp2f((sfA[mt][nt][2] - mstate[nt]) * LOG2E);
        float p3 = exp2f((sfA[mt][nt][3] - mstate[nt]) * LOG2E);
        rsum[nt] += (p0 + p1) + (p2 + p3);
        pk[0] = f2bf(p0); pk[1] = f2bf(p1); pk[2] = f2bf(p2); pk[3] = f2bf(p3);
        *(us4*)&PsW[(nt * 16 + l15) * 40 + mt * 16 + quad * 4] = pk;
      }
    {
      bf16x8 ap[2];
#pragma unroll
      for (int nt = 0; nt < 2; ++nt)
        ap[nt] = *(const bf16x8*)&PsW[(nt * 16 + l15) * 40 + quad * 8];
#pragma unroll
      for (int dt = 0; dt < 8; ++dt)
#pragma unroll
        for (int nt = 0; nt < 2; ++nt)
          o[dt][nt] = __builtin_amdgcn_mfma_f32_16x16x32_bf16(bvA[dt], ap[nt], o[dt][nt], 0, 0, 0);
    }
    // compiler-level fence: Ps slot reused for P_B; forbid hoisting B writes above A reads
    asm volatile("" ::: "memory");
    // P_B -> same Ps slot (RNE), PV_B
#pragma unroll
    for (int nt = 0; nt < 2; ++nt)
#pragma unroll
      for (int mt = 0; mt < 2; ++mt) {
        us4 pk;
        float p0 = exp2f((sfB[mt][nt][0] - mstate[nt]) * LOG2E);
        float p1 = exp2f((sfB[mt][nt][1] - mstate[nt]) * LOG2E);
        float p2 = exp2f((sfB[mt][nt][2] - mstate[nt]) * LOG2E);
        float p3 = exp2f((sfB[mt][nt][3] - mstate[nt]) * LOG2E);
        rsum[nt] += (p0 + p1) + (p2 + p3);
        pk[0] = f2bf(p0); pk[1] = f2bf(p1); pk[2] = f2bf(p2); pk[3] = f2bf(p3);
        *(us4*)&PsW[(nt * 16 + l15) * 40 + mt * 16 + quad * 4] = pk;
      }
    {
      bf16x8 ap[2];
#pragma unroll
      for (int nt = 0; nt < 2; ++nt)
        ap[nt] = *(const bf16x8*)&PsW[(nt * 16 + l15) * 40 + quad * 8];
#pragma unroll
      for (int dt = 0; dt < 8; ++dt)
#pragma unroll
        for (int nt = 0; nt < 2; ++nt)
          o[dt][nt] = __builtin_amdgcn_mfma_f32_16x16x32_bf16(bvB[dt], ap[nt], o[dt][nt], 0, 0, 0);
    }
#pragma unroll
    for (int nt = 0; nt < 2; ++nt) {
      rsum[nt] += __shfl_xor(rsum[nt], 16);
      rsum[nt] += __shfl_xor(rsum[nt], 32);
      lstate[nt] = lstate[nt] * alpha[nt] + rsum[nt];
    }
    __syncthreads();                       // buf1 consumed by all waves
    if (jt + 1 < T_SZ / 128) stage_k(Kg, Ks[1], kbase0, 2 * jt + 3, tid);
  }

  // merge kv-halves: wave (qh,1) sends (m,l,O^T) to wave (qh,0) via dead buffers
  float* Xch = (float*)Ks;   // 32 KB: [qh][dt*2+nt][lane]
  float* st  = (float*)Ps;   // m[64], l[64]
  if (kh == 1) {
#pragma unroll
    for (int dt = 0; dt < 8; ++dt)
#pragma unroll
      for (int nt = 0; nt < 2; ++nt)
        *(f32x4*)&Xch[((qh * 16 + dt * 2 + nt) * 64 + lane) * 4] = o[dt][nt];
    if (quad == 0) {
#pragma unroll
      for (int nt = 0; nt < 2; ++nt) {
        int q = qh * 32 + nt * 16 + l15;
        st[q] = mstate[nt];
        st[64 + q] = lstate[nt];
      }
    }
  }
  __syncthreads();
  if (kh == 0) {
#pragma unroll
    for (int nt = 0; nt < 2; ++nt) {
      int q = qh * 32 + nt * 16 + l15;
      float m1 = st[q], l1 = st[64 + q];
      float M = fmaxf(mstate[nt], m1);
      float a0 = exp2f((mstate[nt] - M) * LOG2E);
      float a1 = exp2f((m1 - M) * LOG2E);
      float L = lstate[nt] * a0 + l1 * a1;
      float inv = 1.0f / L;
      size_t row = (size_t)(b * T_SZ + qt * 64) + q;
#pragma unroll
      for (int dt = 0; dt < 8; ++dt) {
        f32x4 o1 = *(const f32x4*)&Xch[((qh * 16 + dt * 2 + nt) * 64 + lane) * 4];
        us4 pk;
        pk[0] = f2bf((o[dt][nt][0] * a0 + o1[0] * a1) * inv);
        pk[1] = f2bf((o[dt][nt][1] * a0 + o1[1] * a1) * inv);
        pk[2] = f2bf((o[dt][nt][2] * a0 + o1[2] * a1) * inv);
        pk[3] = f2bf((o[dt][nt][3] * a0 + o1[3] * a1) * inv);
        *(us4*)&Y[row * C_SZ + h * D_SZ + dt * 16 + quad * 4] = pk;
      }
    }
  }
}

extern "C" void kernel_launch(void* const* d_in, const int* in_sizes, int n_in,
                              void* d_out, int out_size, void* d_ws, size_t ws_size,
                              hipStream_t stream) {
  (void)in_sizes; (void)n_in; (void)out_size; (void)ws_size;
  const float* x    = (const float*)d_in[0];
  const float* cosp = (const float*)d_in[1];
  const float* sinp = (const float*)d_in[2];
  const float* wq   = (const float*)d_in[3];
  const float* wk   = (const float*)d_in[4];
  const float* wv   = (const float*)d_in[5];
  const float* wo   = (const float*)d_in[6];
  float* out = (float*)d_out;

  const size_t XE = (size_t)B_SZ * T_SZ * C_SZ;  // 16,777,216 elements
  const size_t WE = (size_t)C_SZ * C_SZ;         // 4,194,304 elements
  unsigned short* Xb = (unsigned short*)d_ws;    // bf16 x          (33.5 MB)
  unsigned short* Qb = Xb + XE;                  // roped+scaled Q  (33.5 MB)
  unsigned short* Kb = Qb + XE;                  // roped K         (33.5 MB)
  unsigned short* Vt = Kb + XE;                  // V transposed    (33.5 MB)
  unsigned short* Wb = Vt + XE;                  // weight slot     ( 8.4 MB)
  unsigned short* Y  = Xb;                       // alias: Xb dead after V GEMM

  const int M = B_SZ * T_SZ, N = C_SZ, K = C_SZ;
  dim3 ggrid(N / 256, M / 256);                  // (8, 32) = 256 blocks, 1/CU
  int nbx = (int)(XE / 4 / 256);
  int nbw = (int)(WE / 4 / 256);
  const float qscale = 0.088388347648318447f;  // 1/sqrt(128)  (R3 numerics)

  cast_f32_bf16<<<nbx, 256, 0, stream>>>(x, Xb, (int)(XE / 4));

  cast_f32_bf16<<<nbw, 256, 0, stream>>>(wq, Wb, (int)(WE / 4));
  gemm_bt<1><<<ggrid, 512, 0, stream>>>(Xb, Wb, Qb, cosp, sinp, qscale, M, N, K);

  cast_f32_bf16<<<nbw, 256, 0, stream>>>(wk, Wb, (int)(WE / 4));
  gemm_bt<1><<<ggrid, 512, 0, stream>>>(Xb, Wb, Kb, cosp, sinp, 1.0f, M, N, K);

  cast_f32_bf16<<<nbw, 256, 0, stream>>>(wv, Wb, (int)(WE / 4));
  gemm_bt<2><<<ggrid, 512, 0, stream>>>(Xb, Wb, Vt, nullptr, nullptr, 1.0f, M, N, K);

  attn_fused<<<dim3(T_SZ / 64, B_SZ * H_SZ), 256, 0, stream>>>(Qb, Kb, Vt, Y);

  cast_f32_bf16<<<nbw, 256, 0, stream>>>(wo, Wb, (int)(WE / 4));
  gemm_bt<3><<<ggrid, 512, 0, stream>>>(Y, Wb, out, nullptr, nullptr, 1.0f, M, N, K);
}

// Round 6
// 724.899 us; speedup vs baseline: 1.9430x; 1.9430x over previous
//
#include <hip/hip_runtime.h>

#define B_SZ 4
#define T_SZ 2048
#define C_SZ 2048
#define H_SZ 16
#define D_SZ 128

typedef __attribute__((ext_vector_type(8))) __bf16 bf16x8;
typedef __attribute__((ext_vector_type(4))) float f32x4;
typedef __attribute__((ext_vector_type(4))) unsigned short us4;

// RNE f32->bf16 bit-trick. VERIFIED: the only correct RNE path on this
// toolchain — both (__bf16) casts and v_cvt_pk_bf16_f32 TRUNCATE (R3/R4:
// coherent 0.5-ulp bias over K=2048 dot products -> absmax 0.11-0.34).
static __device__ __forceinline__ unsigned short f2bf(float f) {
  unsigned u = __builtin_bit_cast(unsigned, f);
  u += 0x7fffu + ((u >> 16) & 1u);
  return (unsigned short)(u >> 16);
}

static __device__ __forceinline__ void gload16(const void* g, void* l) {
  __builtin_amdgcn_global_load_lds((__attribute__((address_space(1))) void*)(g),
                                   (__attribute__((address_space(3))) void*)(l), 16, 0, 0);
}

__global__ __launch_bounds__(256) void cast_f32_bf16(const float* __restrict__ src,
                                                     unsigned short* __restrict__ dst, int n4) {
  int i = blockIdx.x * 256 + threadIdx.x;
  if (i >= n4) return;
  float4 v = ((const float4*)src)[i];
  us4 o;
  o[0] = f2bf(v.x); o[1] = f2bf(v.y); o[2] = f2bf(v.z); o[3] = f2bf(v.w);
  ((us4*)dst)[i] = o;
}

// C[m,n] = sum_k A[m,k]*W[n,k].  A: MxK bf16 row-major, W: NxK bf16 row-major.
// BM=BN=256, BK=64, 512 thr = 8 waves (4M x 2N), per-wave 64x128 (acc[4][8]).
// Double-buffered LDS (128 KB).  Per K-tile: vmcnt(8)+barrier at top (tile t
// landed; t+1's 8 loads stay in flight across all barriers = T4), then 4
// phases of {ds_read quadrant frags; setprio(1); 16 MFMA; setprio(0); barrier}.
// R6: pre-MFMA barrier REMOVED (it fenced read-vs-read only) — waves now slip
// within a phase so one wave's ds_reads overlap another's MFMAs; the trailing
// phase barrier provides the WAR fence for the STAGE target buffer.
// LDS XOR-swizzle: 16B col-chunk ^= (row&7) via pre-permuted GLOBAL source
// (linear gload_lds dest) and the same XOR on ds_read addresses.
// EPI 1: RoPE epilogue -> bf16; EPI 2: transposed store -> Vt; EPI 3: fp32 store
template <int EPI>
__global__ __launch_bounds__(512, 2) void gemm_bt(const unsigned short* __restrict__ A,
                                                  const unsigned short* __restrict__ W,
                                                  void* __restrict__ out,
                                                  const float* __restrict__ cosp,
                                                  const float* __restrict__ sinp,
                                                  float outScale, int M, int N, int K) {
  __shared__ unsigned short As[2][256 * 64];  // 2 x 32 KB
  __shared__ unsigned short Bs[2][256 * 64];  // 2 x 32 KB
  const int tid = threadIdx.x;
  const int wave = tid >> 6, lane = tid & 63, quad = lane >> 4, l15 = lane & 15;
  const int wm = wave >> 1, wn = wave & 1;
  const int m0 = blockIdx.y * 256, n0 = blockIdx.x * 256;
  const int NT = K >> 6;

  // staging: per operand slot = 2048 chunks of 16B; chunk i: row=i>>3, c8=i&7,
  // swizzled k-chunk = c8 ^ (row&7).  thread covers chunks j*512+tid, j=0..3.
  const int srow = tid >> 3;
  const int kcol = ((tid & 7) ^ (srow & 7)) * 8;
  const unsigned short* aptr = A + (size_t)(m0 + srow) * K + kcol;
  const unsigned short* bptr = W + (size_t)(n0 + srow) * K + kcol;
  const int ldst = tid * 16;  // byte offset of chunk j=0 in a slot

#define STAGE(t)                                                                   \
  do {                                                                             \
    const int sl_ = (t) & 1;                                                       \
    const size_t kk_ = (size_t)(t) * 64;                                           \
    _Pragma("unroll") for (int j = 0; j < 4; ++j) {                                \
      gload16(aptr + (size_t)j * 64 * K + kk_, (char*)As[sl_] + j * 8192 + ldst);  \
      gload16(bptr + (size_t)j * 64 * K + kk_, (char*)Bs[sl_] + j * 8192 + ldst);  \
    }                                                                              \
  } while (0)

  f32x4 acc[4][8] = {};
  const int swz = l15 & 7;

  STAGE(0);  // 8 loads in flight
  for (int t = 0; t < NT; ++t) {
    if (t + 1 < NT) {
      STAGE(t + 1);  // now up to 16 in flight
      asm volatile("s_waitcnt vmcnt(8)" ::: "memory");  // tile t landed; t+1 stays in flight
    } else {
      asm volatile("s_waitcnt vmcnt(0)" ::: "memory");  // tail drain (once)
    }
    __builtin_amdgcn_s_barrier();
    asm volatile("" ::: "memory");
    const unsigned short* Asl = As[t & 1];
    const unsigned short* Bsl = Bs[t & 1];
    bf16x8 af[4];
#pragma unroll
    for (int p = 0; p < 4; ++p) {
      const int ks = p >> 1, nh = p & 1;  // quadrant = (kstep, n-half)
      if (nh == 0) {
#pragma unroll
        for (int mf = 0; mf < 4; ++mf)
          af[mf] = *(const bf16x8*)&Asl[(wm * 64 + mf * 16 + l15) * 64 +
                                        (((ks * 4 + quad) ^ swz) * 8)];
      }
      bf16x8 bfr[4];
#pragma unroll
      for (int i = 0; i < 4; ++i)
        bfr[i] = *(const bf16x8*)&Bsl[(wn * 128 + (nh * 4 + i) * 16 + l15) * 64 +
                                      (((ks * 4 + quad) ^ swz) * 8)];
      __builtin_amdgcn_s_setprio(1);
#pragma unroll
      for (int i = 0; i < 4; ++i)
#pragma unroll
        for (int mf = 0; mf < 4; ++mf)
          acc[mf][nh * 4 + i] =
              __builtin_amdgcn_mfma_f32_16x16x32_bf16(af[mf], bfr[i], acc[mf][nh * 4 + i], 0, 0, 0);
      __builtin_amdgcn_s_setprio(0);
      __builtin_amdgcn_s_barrier();   // phase pacing + WAR fence for STAGE target
      asm volatile("" ::: "memory");
    }
  }
#undef STAGE

  const int mb = m0 + wm * 64, nb = n0 + wn * 128;
  if (EPI == 1) {
    unsigned short* O = (unsigned short*)out;
#pragma unroll
    for (int mf = 0; mf < 4; ++mf)
#pragma unroll
      for (int r = 0; r < 4; ++r) {
        int m = mb + mf * 16 + quad * 4 + r;
        int tt = m & (T_SZ - 1);
#pragma unroll
        for (int nf = 0; nf < 4; ++nf) {
          int dd = nf * 16 + l15;
          float c = cosp[tt * 64 + dd];
          float s = sinp[tt * 64 + dd];
          float x1 = acc[mf][nf][r], x2 = acc[mf][nf + 4][r];
          O[(size_t)m * N + nb + dd]      = f2bf((x1 * c + x2 * s) * outScale);
          O[(size_t)m * N + nb + dd + 64] = f2bf((x1 * c - x2 * s) * outScale);
        }
      }
  } else if (EPI == 2) {
    unsigned short* O = (unsigned short*)out;
#pragma unroll
    for (int mf = 0; mf < 4; ++mf) {
      int m4 = mb + mf * 16 + quad * 4;  // 4 consecutive rows (same b)
      int bb = m4 >> 11;
      int tt = m4 & (T_SZ - 1);
#pragma unroll
      for (int nf = 0; nf < 8; ++nf) {
        int n = nb + nf * 16 + l15;
        int h = n >> 7, d = n & (D_SZ - 1);
        us4 pk;
        pk[0] = f2bf(acc[mf][nf][0]);
        pk[1] = f2bf(acc[mf][nf][1]);
        pk[2] = f2bf(acc[mf][nf][2]);
        pk[3] = f2bf(acc[mf][nf][3]);
        *(us4*)&O[((size_t)((bb * H_SZ + h) * D_SZ + d)) * T_SZ + tt] = pk;
      }
    }
  } else {
    float* O = (float*)out;
#pragma unroll
    for (int mf = 0; mf < 4; ++mf)
#pragma unroll
      for (int nf = 0; nf < 8; ++nf)
#pragma unroll
        for (int r = 0; r < 4; ++r) {
          int m = mb + mf * 16 + quad * 4 + r;
          O[(size_t)m * N + nb + nf * 16 + l15] = acc[mf][nf][r];
        }
  }
}

static __device__ __forceinline__ void stage_kv(const unsigned short* __restrict__ Kg,
                                                const unsigned short* __restrict__ Vt,
                                                unsigned short* Kbuf, unsigned short* Vbuf,
                                                size_t kbase0, size_t vbase0, int kt, int tid) {
  size_t kb = kbase0 + (size_t)kt * 64 * C_SZ;
  size_t vb = vbase0 + (size_t)kt * 64;
#pragma unroll
  for (int s = 0; s < 4; ++s) {
    int ii = s * 256 + tid;
    int krow = ii >> 4, kpos = ii & 15, kc = kpos ^ (krow & 15);
    gload16(Kg + kb + (size_t)krow * C_SZ + kc * 8, (char*)Kbuf + ii * 16);
    int vrow = ii >> 3, vpos = ii & 7, vc = vpos ^ (vrow & 7);
    gload16(Vt + vb + (size_t)vrow * T_SZ + vc * 8, (char*)Vbuf + ii * 16);
  }
}

// Flash attention — R2-exact known-good version (271 us, passed).
// R5 lesson: V must stay LDS-staged via gload_lds (dense 128KB sweeps);
// direct per-fragment global V reads (64B/row scattered) thrashed L2 ->
// 7x HBM fetch, kernel went HBM-bound (52%) and 3.4x slower.
// RNE (f2bf) on all P and Y packing; softmax in e-base with fp32 LOG2E mul
// (Q pre-scaled by 1/sqrt(d) only). Waves 2x2 (q-half x kv-half); S transposed;
// K/V double-buffered; paired kv-tiles; Ps wave-private slot reuse + fence.
__global__ __launch_bounds__(256, 2) void attn_fused(const unsigned short* __restrict__ Q,
                                                     const unsigned short* __restrict__ Kg,
                                                     const unsigned short* __restrict__ Vt,
                                                     unsigned short* __restrict__ Y) {
  __shared__ unsigned short Ks[2][64 * 128];   // 32 KB (dbuf)
  __shared__ unsigned short Vs[2][128 * 64];   // 32 KB (dbuf), [d][kv]
  __shared__ unsigned short Ps[4][32 * 40];    // 10 KB, per-wave P[q32][kv32]
  const int tid = threadIdx.x;
  const int wave = tid >> 6, lane = tid & 63, quad = lane >> 4, l15 = lane & 15;
  const int kh = wave & 1, qh = wave >> 1;
  const int qt = blockIdx.x, bh = blockIdx.y;
  const int b = bh >> 4, h = bh & 15;
  const float LOG2E = 1.44269504088896f;

  // Q fragments direct to registers (B-operand: n=q in l15, k contiguous)
  bf16x8 aq[2][4];
  {
    size_t qrow0 = (size_t)(b * T_SZ + qt * 64 + qh * 32);
#pragma unroll
    for (int nt = 0; nt < 2; ++nt)
#pragma unroll
      for (int ks = 0; ks < 4; ++ks)
        aq[nt][ks] = *(const bf16x8*)(Q + (qrow0 + nt * 16 + l15) * C_SZ + h * D_SZ + ks * 32 + quad * 8);
  }

  const size_t kbase0 = ((size_t)(b * T_SZ)) * C_SZ + h * D_SZ;
  const size_t vbase0 = ((size_t)(bh * D_SZ)) * T_SZ;
  stage_kv(Kg, Vt, Ks[0], Vs[0], kbase0, vbase0, 0, tid);
  stage_kv(Kg, Vt, Ks[1], Vs[1], kbase0, vbase0, 1, tid);

  float mstate[2] = {-1e30f, -1e30f}, lstate[2] = {0.f, 0.f};
  f32x4 o[8][2] = {};
  unsigned short* PsW = Ps[wave];
  __syncthreads();   // tiles 0,1 staged (vmcnt drained); aq ready

  for (int jt = 0; jt < T_SZ / 128; ++jt) {
    // ---- tile A (buf0): frags -> regs, S_A
    bf16x8 bkA[2][4], bvA[8];
#pragma unroll
    for (int mt = 0; mt < 2; ++mt)
#pragma unroll
      for (int ks = 0; ks < 4; ++ks)
        bkA[mt][ks] = *(const bf16x8*)&Ks[0][(kh * 32 + mt * 16 + l15) * 128 + (((ks * 4 + quad) ^ l15) * 8)];
#pragma unroll
    for (int dt = 0; dt < 8; ++dt)
      bvA[dt] = *(const bf16x8*)&Vs[0][(dt * 16 + l15) * 64 + (((kh * 4 + quad) ^ (l15 & 7)) * 8)];
    f32x4 sfA[2][2] = {};
#pragma unroll
    for (int mt = 0; mt < 2; ++mt)
#pragma unroll
      for (int ks = 0; ks < 4; ++ks)
#pragma unroll
        for (int nt = 0; nt < 2; ++nt)
          sfA[mt][nt] = __builtin_amdgcn_mfma_f32_16x16x32_bf16(bkA[mt][ks], aq[nt][ks], sfA[mt][nt], 0, 0, 0);
    __syncthreads();                       // buf0 consumed by all waves
    if (jt + 1 < T_SZ / 128) stage_kv(Kg, Vt, Ks[0], Vs[0], kbase0, vbase0, 2 * jt + 2, tid);
    // ---- tile B (buf1): frags -> regs, S_B
    bf16x8 bkB[2][4], bvB[8];
#pragma unroll
    for (int mt = 0; mt < 2; ++mt)
#pragma unroll
      for (int ks = 0; ks < 4; ++ks)
        bkB[mt][ks] = *(const bf16x8*)&Ks[1][(kh * 32 + mt * 16 + l15) * 128 + (((ks * 4 + quad) ^ l15) * 8)];
#pragma unroll
    for (int dt = 0; dt < 8; ++dt)
      bvB[dt] = *(const bf16x8*)&Vs[1][(dt * 16 + l15) * 64 + (((kh * 4 + quad) ^ (l15 & 7)) * 8)];
    f32x4 sfB[2][2] = {};
#pragma unroll
    for (int mt = 0; mt < 2; ++mt)
#pragma unroll
      for (int ks = 0; ks < 4; ++ks)
#pragma unroll
        for (int nt = 0; nt < 2; ++nt)
          sfB[mt][nt] = __builtin_amdgcn_mfma_f32_16x16x32_bf16(bkB[mt][ks], aq[nt][ks], sfB[mt][nt], 0, 0, 0);
    // ---- paired online softmax (e-base, fp32 LOG2E; q = nt*16+l15 per-lane scalar)
    float alpha[2], rsum[2];
#pragma unroll
    for (int nt = 0; nt < 2; ++nt) {
      float rmax = sfA[0][nt][0];
#pragma unroll
      for (int mt = 0; mt < 2; ++mt)
#pragma unroll
        for (int r = 0; r < 4; ++r) {
          rmax = fmaxf(rmax, sfA[mt][nt][r]);
          rmax = fmaxf(rmax, sfB[mt][nt][r]);
        }
      rmax = fmaxf(rmax, __shfl_xor(rmax, 16));
      rmax = fmaxf(rmax, __shfl_xor(rmax, 32));
      float mnew = fmaxf(mstate[nt], rmax);
      alpha[nt] = exp2f((mstate[nt] - mnew) * LOG2E);
      mstate[nt] = mnew;
      rsum[nt] = 0.f;
    }
    // one O-rescale per 128 kv
#pragma unroll
    for (int dt = 0; dt < 8; ++dt)
#pragma unroll
      for (int nt = 0; nt < 2; ++nt)
        o[dt][nt] *= alpha[nt];
    // P_A -> Ps (RNE), PV_A
#pragma unroll
    for (int nt = 0; nt < 2; ++nt)
#pragma unroll
      for (int mt = 0; mt < 2; ++mt) {
        us4 pk;
        float p0 = exp2f((sfA[mt][nt][0] - mstate[nt]) * LOG2E);
        float p1 = exp2f((sfA[mt][nt][1] - mstate[nt]) * LOG2E);
        float p2 = exp2f((sfA[mt][nt][2] - mstate[nt]) * LOG2E);
        float p3 = exp2f((sfA[mt][nt][3] - mstate[nt]) * LOG2E);
        rsum[nt] += (p0 + p1) + (p2 + p3);
        pk[0] = f2bf(p0); pk[1] = f2bf(p1); pk[2] = f2bf(p2); pk[3] = f2bf(p3);
        *(us4*)&PsW[(nt * 16 + l15) * 40 + mt * 16 + quad * 4] = pk;
      }
    {
      bf16x8 ap[2];
#pragma unroll
      for (int nt = 0; nt < 2; ++nt)
        ap[nt] = *(const bf16x8*)&PsW[(nt * 16 + l15) * 40 + quad * 8];
#pragma unroll
      for (int dt = 0; dt < 8; ++dt)
#pragma unroll
        for (int nt = 0; nt < 2; ++nt)
          o[dt][nt] = __builtin_amdgcn_mfma_f32_16x16x32_bf16(bvA[dt], ap[nt], o[dt][nt], 0, 0, 0);
    }
    // compiler-level fence: Ps slot reused for P_B; forbid hoisting B writes above A reads
    asm volatile("" ::: "memory");
    // P_B -> same Ps slot (RNE), PV_B
#pragma unroll
    for (int nt = 0; nt < 2; ++nt)
#pragma unroll
      for (int mt = 0; mt < 2; ++mt) {
        us4 pk;
        float p0 = exp2f((sfB[mt][nt][0] - mstate[nt]) * LOG2E);
        float p1 = exp2f((sfB[mt][nt][1] - mstate[nt]) * LOG2E);
        float p2 = exp2f((sfB[mt][nt][2] - mstate[nt]) * LOG2E);
        float p3 = exp2f((sfB[mt][nt][3] - mstate[nt]) * LOG2E);
        rsum[nt] += (p0 + p1) + (p2 + p3);
        pk[0] = f2bf(p0); pk[1] = f2bf(p1); pk[2] = f2bf(p2); pk[3] = f2bf(p3);
        *(us4*)&PsW[(nt * 16 + l15) * 40 + mt * 16 + quad * 4] = pk;
      }
    {
      bf16x8 ap[2];
#pragma unroll
      for (int nt = 0; nt < 2; ++nt)
        ap[nt] = *(const bf16x8*)&PsW[(nt * 16 + l15) * 40 + quad * 8];
#pragma unroll
      for (int dt = 0; dt < 8; ++dt)
#pragma unroll
        for (int nt = 0; nt < 2; ++nt)
          o[dt][nt] = __builtin_amdgcn_mfma_f32_16x16x32_bf16(bvB[dt], ap[nt], o[dt][nt], 0, 0, 0);
    }
#pragma unroll
    for (int nt = 0; nt < 2; ++nt) {
      rsum[nt] += __shfl_xor(rsum[nt], 16);
      rsum[nt] += __shfl_xor(rsum[nt], 32);
      lstate[nt] = lstate[nt] * alpha[nt] + rsum[nt];
    }
    __syncthreads();                       // buf1 consumed by all waves
    if (jt + 1 < T_SZ / 128) stage_kv(Kg, Vt, Ks[1], Vs[1], kbase0, vbase0, 2 * jt + 3, tid);
  }

  // merge kv-halves: wave (qh,1) sends (m,l,O^T) to wave (qh,0) via dead K/V buffers
  float* Xch = (float*)Ks;   // 32 KB: [qh][dt*2+nt][lane]
  float* st  = (float*)Vs;   // m[64], l[64]
  if (kh == 1) {
#pragma unroll
    for (int dt = 0; dt < 8; ++dt)
#pragma unroll
      for (int nt = 0; nt < 2; ++nt)
        *(f32x4*)&Xch[((qh * 16 + dt * 2 + nt) * 64 + lane) * 4] = o[dt][nt];
    if (quad == 0) {
#pragma unroll
      for (int nt = 0; nt < 2; ++nt) {
        int q = qh * 32 + nt * 16 + l15;
        st[q] = mstate[nt];
        st[64 + q] = lstate[nt];
      }
    }
  }
  __syncthreads();
  if (kh == 0) {
#pragma unroll
    for (int nt = 0; nt < 2; ++nt) {
      int q = qh * 32 + nt * 16 + l15;
      float m1 = st[q], l1 = st[64 + q];
      float M = fmaxf(mstate[nt], m1);
      float a0 = exp2f((mstate[nt] - M) * LOG2E);
      float a1 = exp2f((m1 - M) * LOG2E);
      float L = lstate[nt] * a0 + l1 * a1;
      float inv = 1.0f / L;
      size_t row = (size_t)(b * T_SZ + qt * 64) + q;
#pragma unroll
      for (int dt = 0; dt < 8; ++dt) {
        f32x4 o1 = *(const f32x4*)&Xch[((qh * 16 + dt * 2 + nt) * 64 + lane) * 4];
        us4 pk;
        pk[0] = f2bf((o[dt][nt][0] * a0 + o1[0] * a1) * inv);
        pk[1] = f2bf((o[dt][nt][1] * a0 + o1[1] * a1) * inv);
        pk[2] = f2bf((o[dt][nt][2] * a0 + o1[2] * a1) * inv);
        pk[3] = f2bf((o[dt][nt][3] * a0 + o1[3] * a1) * inv);
        *(us4*)&Y[row * C_SZ + h * D_SZ + dt * 16 + quad * 4] = pk;
      }
    }
  }
}

extern "C" void kernel_launch(void* const* d_in, const int* in_sizes, int n_in,
                              void* d_out, int out_size, void* d_ws, size_t ws_size,
                              hipStream_t stream) {
  (void)in_sizes; (void)n_in; (void)out_size; (void)ws_size;
  const float* x    = (const float*)d_in[0];
  const float* cosp = (const float*)d_in[1];
  const float* sinp = (const float*)d_in[2];
  const float* wq   = (const float*)d_in[3];
  const float* wk   = (const float*)d_in[4];
  const float* wv   = (const float*)d_in[5];
  const float* wo   = (const float*)d_in[6];
  float* out = (float*)d_out;

  const size_t XE = (size_t)B_SZ * T_SZ * C_SZ;  // 16,777,216 elements
  const size_t WE = (size_t)C_SZ * C_SZ;         // 4,194,304 elements
  unsigned short* Xb = (unsigned short*)d_ws;    // bf16 x          (33.5 MB)
  unsigned short* Qb = Xb + XE;                  // roped+scaled Q  (33.5 MB)
  unsigned short* Kb = Qb + XE;                  // roped K         (33.5 MB)
  unsigned short* Vt = Kb + XE;                  // V transposed    (33.5 MB)
  unsigned short* Wb = Vt + XE;                  // weight slot     ( 8.4 MB)
  unsigned short* Y  = Xb;                       // alias: Xb dead after V GEMM

  const int M = B_SZ * T_SZ, N = C_SZ, K = C_SZ;
  dim3 ggrid(N / 256, M / 256);                  // (8, 32) = 256 blocks, 1/CU
  int nbx = (int)(XE / 4 / 256);
  int nbw = (int)(WE / 4 / 256);
  const float qscale = 0.088388347648318447f;  // 1/sqrt(128)  (R3 numerics)

  cast_f32_bf16<<<nbx, 256, 0, stream>>>(x, Xb, (int)(XE / 4));

  cast_f32_bf16<<<nbw, 256, 0, stream>>>(wq, Wb, (int)(WE / 4));
  gemm_bt<1><<<ggrid, 512, 0, stream>>>(Xb, Wb, Qb, cosp, sinp, qscale, M, N, K);

  cast_f32_bf16<<<nbw, 256, 0, stream>>>(wk, Wb, (int)(WE / 4));
  gemm_bt<1><<<ggrid, 512, 0, stream>>>(Xb, Wb, Kb, cosp, sinp, 1.0f, M, N, K);

  cast_f32_bf16<<<nbw, 256, 0, stream>>>(wv, Wb, (int)(WE / 4));
  gemm_bt<2><<<ggrid, 512, 0, stream>>>(Xb, Wb, Vt, nullptr, nullptr, 1.0f, M, N, K);

  attn_fused<<<dim3(T_SZ / 64, B_SZ * H_SZ), 256, 0, stream>>>(Qb, Kb, Vt, Y);

  cast_f32_bf16<<<nbw, 256, 0, stream>>>(wo, Wb, (int)(WE / 4));
  gemm_bt<3><<<ggrid, 512, 0, stream>>>(Y, Wb, out, nullptr, nullptr, 1.0f, M, N, K);
}